// Round 2
// baseline (6916.872 us; speedup 1.0000x reference)
//
#include <hip/hip_runtime.h>
#include <cmath>

#define BATCH_  1024
#define DIN     2048
#define HID     512
#define NCLS    151
#define TSTEPS  65
#define NP      3072   /* 6*HID : pi width */
#define NS      2560   /* 5*HID : ps width */

/* d_out layout (floats): dists (B,T,C) | commitments (T,B) | states (B,T,H) */
#define DIST_OFF   0
#define COMMIT_OFF (BATCH_*TSTEPS*NCLS)
#define STATES_OFF (COMMIT_OFF + TSTEPS*BATCH_)

/* workspace layout (float offsets) */
#define WS_STATE  0                          /* 1024 x 512  state (out) */
#define WS_MEM    (WS_STATE + BATCH_*HID)    /* 1024 x 512  memory      */
#define WS_PA     (WS_MEM   + BATCH_*HID)    /* 1024 x 2560 ps partial K0 */
#define WS_PB     (WS_PA    + BATCH_*NS)     /* 1024 x 2560 ps partial K1 */
#define WS_P0     (WS_PB    + BATCH_*NS)     /* 1024 x 3072 pi at t=0   */
#define WS_E0     (WS_P0    + BATCH_*NP)     /* 1024 x 512  embed0      */
#define WS_T0T    (WS_E0    + BATCH_*HID)    /* 151 x 3072  pi table    */
#define WS_T1B    (WS_T0T   + NCLS*NP)       /* 3072        W_in@b_onehot + b_in */
#define WS_WOUTT  (WS_T1B   + NP)            /* 512 x 151   W_out^T     */
#define WS_LIST   (WS_WOUTT + HID*NCLS)      /* int: 1024 cnt + 1024*8 list */

/* ------------------------------------------------------------------ */
/* Prep: transpose W_out; zero memory and ps partials.                */
__global__ __launch_bounds__(256) void prep_kernel(
    const float* __restrict__ W_out, float* __restrict__ WoutT,
    float* __restrict__ memB, float* __restrict__ P_a, float* __restrict__ P_b)
{
    int idx = blockIdx.x * 256 + threadIdx.x;
    int stride = gridDim.x * 256;
    for (int i = idx; i < HID * NCLS; i += stride) {
        int k = i / NCLS, c = i % NCLS;
        WoutT[i] = W_out[c * HID + k];
    }
    for (int i = idx; i < BATCH_ * HID; i += stride) memB[i] = 0.f;
    for (int i = idx; i < BATCH_ * NS; i += stride) { P_a[i] = 0.f; P_b[i] = 0.f; }
}

/* T0T[c][n] = sum_h W_in[n,h] * W_onehot[h,c]   (one-time)           */
__global__ __launch_bounds__(256) void tab_kernel(
    const float* __restrict__ W_in, const float* __restrict__ W_onehot,
    float* __restrict__ T0T)
{
    int nt = blockIdx.x % 48, ct = blockIdx.x / 48;      /* 48 x 5 blocks */
    int n  = nt * 64 + (threadIdx.x & 63);
    int q  = threadIdx.x >> 6;                           /* 0..3 */
    int c0 = ct * 32 + q * 8;
    float acc[8] = {};
    for (int h = 0; h < HID; ++h) {
        float w = W_in[(size_t)n * HID + h];
        const float* orow = W_onehot + (size_t)h * NCLS;
        #pragma unroll
        for (int j = 0; j < 8; ++j) {
            int c = c0 + j;
            acc[j] += w * orow[(c < NCLS) ? c : (NCLS - 1)];
        }
    }
    #pragma unroll
    for (int j = 0; j < 8; ++j) {
        int c = c0 + j;
        if (c < NCLS) T0T[(size_t)c * NP + n] = acc[j];
    }
}

/* T1b[n] = b_in[n] + sum_h W_in[n,h] * b_onehot[h]   (one-time)      */
__global__ __launch_bounds__(256) void t1b_kernel(
    const float* __restrict__ W_in, const float* __restrict__ b_onehot,
    const float* __restrict__ b_in, float* __restrict__ T1b)
{
    int n = blockIdx.x * 256 + threadIdx.x;              /* grid 12 */
    float acc = b_in[n];
    for (int h = 0; h < HID; ++h)
        acc += W_in[(size_t)n * HID + h] * b_onehot[h];
    T1b[n] = acc;
}

/* ------------------------------------------------------------------ */
/* Tiled fp32 GEMM segment: acc += A[m0.., k..] * W[n0.., k..]^T      */
#define BM 128
#define BN 64
#define BKK 16

__device__ __forceinline__ void gemm_seg(
    const float* __restrict__ A, int lda,
    const float* __restrict__ W, int ldw,
    int kLen, int m0, int n0,
    float* As, float* Bs, float acc[8][4])
{
    const int tid = threadIdx.x;
    const int ar = tid >> 2;          /* 0..63 */
    const int ak = (tid & 3) << 2;    /* 0,4,8,12 */
    const int tx = tid & 15;
    const int ty = tid >> 4;

    for (int k0 = 0; k0 < kLen; k0 += BKK) {
        float4 a0 = *(const float4*)(A + (size_t)(m0 + ar)      * lda + (k0 + ak));
        float4 a1 = *(const float4*)(A + (size_t)(m0 + ar + 64) * lda + (k0 + ak));
        float4 b0 = *(const float4*)(W + (size_t)(n0 + ar)      * ldw + (k0 + ak));
        __syncthreads();
        As[(ak + 0) * BM + ar]      = a0.x;
        As[(ak + 1) * BM + ar]      = a0.y;
        As[(ak + 2) * BM + ar]      = a0.z;
        As[(ak + 3) * BM + ar]      = a0.w;
        As[(ak + 0) * BM + ar + 64] = a1.x;
        As[(ak + 1) * BM + ar + 64] = a1.y;
        As[(ak + 2) * BM + ar + 64] = a1.z;
        As[(ak + 3) * BM + ar + 64] = a1.w;
        Bs[(ak + 0) * BN + ar] = b0.x;
        Bs[(ak + 1) * BN + ar] = b0.y;
        Bs[(ak + 2) * BN + ar] = b0.z;
        Bs[(ak + 3) * BN + ar] = b0.w;
        __syncthreads();
        #pragma unroll
        for (int kk = 0; kk < BKK; ++kk) {
            float av[8], bv[4];
            *(float4*)(&av[0]) = *(const float4*)(&As[kk * BM + ty * 8]);
            *(float4*)(&av[4]) = *(const float4*)(&As[kk * BM + ty * 8 + 4]);
            *(float4*)(&bv[0]) = *(const float4*)(&Bs[kk * BN + tx * 4]);
            #pragma unroll
            for (int i = 0; i < 8; ++i)
                #pragma unroll
                for (int j = 0; j < 4; ++j)
                    acc[i][j] = fmaf(av[i], bv[j], acc[i][j]);
        }
    }
}

/* per-step: ps partials = state @ W_state^T, split-K(2), 640 blocks  */
__global__ __launch_bounds__(256) void k1_gemm(
    const float* __restrict__ stateA, const float* __restrict__ W_state,
    float* __restrict__ P_a, float* __restrict__ P_b)
{
    __shared__ float As[BKK * BM];
    __shared__ float Bs[BKK * BN];
    float acc[8][4] = {};
    const int bid = blockIdx.x;
    const int ks  = (bid >= 320) ? 1 : 0;
    const int rem = bid - ks * 320;
    const int m0 = (rem & 7) * BM;
    const int n0 = (rem >> 3) * BN;

    gemm_seg(stateA + ks * 256, HID, W_state + ks * 256, HID, 256, m0, n0, As, Bs, acc);

    float* P = ks ? P_b : P_a;
    const int tx = threadIdx.x & 15, ty = threadIdx.x >> 4;
    #pragma unroll
    for (int i = 0; i < 8; ++i) {
        int row = m0 + ty * 8 + i;
        float4 v = make_float4(acc[i][0], acc[i][1], acc[i][2], acc[i][3]);
        *(float4*)(P + (size_t)row * NS + n0 + tx * 4) = v;
    }
}

/* one-time: E0 = inputs @ W_embed^T + b_embed  (grid 8x8)            */
__global__ __launch_bounds__(256) void k0_gemm_embed(
    const float* __restrict__ inputs, const float* __restrict__ W_embed,
    const float* __restrict__ b_embed, float* __restrict__ E0)
{
    __shared__ float As[BKK * BM];
    __shared__ float Bs[BKK * BN];
    float acc[8][4] = {};
    const int m0 = (blockIdx.x & 7) * BM;
    const int n0 = (blockIdx.x >> 3) * BN;

    gemm_seg(inputs, DIN, W_embed, DIN, DIN, m0, n0, As, Bs, acc);

    const int tx = threadIdx.x & 15, ty = threadIdx.x >> 4;
    #pragma unroll
    for (int i = 0; i < 8; ++i) {
        int row = m0 + ty * 8 + i;
        float4 bb = *(const float4*)(b_embed + n0 + tx * 4);
        float4 v = make_float4(acc[i][0] + bb.x, acc[i][1] + bb.y,
                               acc[i][2] + bb.z, acc[i][3] + bb.w);
        *(float4*)(E0 + (size_t)row * HID + n0 + tx * 4) = v;
    }
}

/* one-time: P0 = E0 @ W_in^T  (grid 8x48)                            */
__global__ __launch_bounds__(256) void k1full_gemm(
    const float* __restrict__ E0, const float* __restrict__ W_in,
    float* __restrict__ P0)
{
    __shared__ float As[BKK * BM];
    __shared__ float Bs[BKK * BN];
    float acc[8][4] = {};
    const int m0 = (blockIdx.x & 7) * BM;
    const int n0 = (blockIdx.x >> 3) * BN;

    gemm_seg(E0, HID, W_in, HID, HID, m0, n0, As, Bs, acc);

    const int tx = threadIdx.x & 15, ty = threadIdx.x >> 4;
    #pragma unroll
    for (int i = 0; i < 8; ++i) {
        int row = m0 + ty * 8 + i;
        float4 v = make_float4(acc[i][0], acc[i][1], acc[i][2], acc[i][3]);
        *(float4*)(P0 + (size_t)row * NP + n0 + tx * 4) = v;
    }
}

/* ------------------------------------------------------------------ */
/* K23: pi gather + gates -> out -> logits -> softmax -> argmax/list  */
#define RPB 4   /* rows per block; one wave per row in phase B */

__global__ __launch_bounds__(256) void k23_step(
    const float* __restrict__ P_a, const float* __restrict__ P_b,
    const float* __restrict__ P0,  const float* __restrict__ T0T,
    const float* __restrict__ T1b,
    float* __restrict__ memB, float* __restrict__ stateA,
    const float* __restrict__ WoutT,
    const float* __restrict__ b_in, const float* __restrict__ b_state,
    const float* __restrict__ b_out,
    const int* __restrict__ obj_num,
    int* __restrict__ prevCnt, int* __restrict__ prevList,
    float* __restrict__ dout, int t)
{
    __shared__ float outS[RPB][HID];
    __shared__ int cntS[RPB];
    __shared__ int listS[RPB][8];

    const int tid = threadIdx.x;
    const int r0 = blockIdx.x * RPB;
    if (tid < RPB) cntS[tid] = 0;

    /* Phase A: pi (table or P0) + ps -> gates -> out/state/mem */
    for (int idx = tid; idx < RPB * HID; idx += 256) {
        int r = idx >> 9, h = idx & (HID - 1);
        int b = r0 + r;
        float pi[6];
        if (t == 0) {
            #pragma unroll
            for (int j = 0; j < 6; ++j)
                pi[j] = P0[(size_t)b * NP + j * HID + h] + b_in[j * HID + h];
        } else {
            #pragma unroll
            for (int j = 0; j < 6; ++j) pi[j] = T1b[j * HID + h];
            int cnt = prevCnt[b];
            for (int i = 0; i < cnt; ++i) {
                const float* trow = T0T + (size_t)prevList[b * 8 + i] * NP;
                #pragma unroll
                for (int j = 0; j < 6; ++j) pi[j] += trow[j * HID + h];
            }
        }
        float x[5];
        #pragma unroll
        for (int j = 0; j < 5; ++j)
            x[j] = pi[j] + P_a[(size_t)b * NS + j * HID + h]
                         + P_b[(size_t)b * NS + j * HID + h]
                         + b_state[j * HID + h];
        float ig = 1.f / (1.f + expf(-x[0]));
        float fg = 1.f / (1.f + expf(-x[1]));
        float mi = tanhf(x[2]);
        float og = 1.f / (1.f + expf(-x[3]));
        float hg = 1.f / (1.f + expf(-x[4]));
        float mo = memB[(size_t)b * HID + h];
        float nm = ig * mi + fg * mo;
        memB[(size_t)b * HID + h] = nm;
        float o  = og * tanhf(nm);
        o = hg * o + (1.f - hg) * pi[5];
        outS[r][h] = o;
        stateA[(size_t)b * HID + h] = o;                  /* state_{t+1} */
        float mk = (t < obj_num[b]) ? 1.f : 0.f;
        dout[STATES_OFF + (size_t)b * (TSTEPS * HID) + (size_t)t * HID + h] = o * mk;
    }
    __syncthreads();

    /* Phase B: one wave per row -> logits, softmax, argmax, match list */
    const int wave = tid >> 6, lane = tid & 63;
    {
        int r = wave;
        int b = r0 + r;
        int c0 = lane;            /* < 151 */
        int c1 = 64 + lane;       /* < 151 */
        int c2 = 128 + lane;
        bool v2 = (c2 < NCLS);
        int c2c = v2 ? c2 : (NCLS - 1);

        float a0 = b_out[c0], a1 = b_out[c1], a2 = b_out[c2c];
        #pragma unroll 4
        for (int k = 0; k < HID; ++k) {
            float ov = outS[r][k];
            const float* wr = WoutT + (size_t)k * NCLS;
            a0 = fmaf(ov, wr[c0], a0);
            a1 = fmaf(ov, wr[c1], a1);
            a2 = fmaf(ov, wr[c2c], a2);
        }

        float mx = fmaxf(a0, a1);
        if (v2) mx = fmaxf(mx, a2);
        #pragma unroll
        for (int off = 32; off; off >>= 1) mx = fmaxf(mx, __shfl_xor(mx, off));
        float e0 = expf(a0 - mx), e1 = expf(a1 - mx);
        float e2 = v2 ? expf(a2 - mx) : 0.f;
        float sm = e0 + e1 + e2;
        #pragma unroll
        for (int off = 32; off; off >>= 1) sm += __shfl_xor(sm, off);
        float d0 = e0 / sm, d1 = e1 / sm, d2 = e2 / sm;

        float mk = (t < obj_num[b]) ? 1.f : 0.f;
        size_t dbase = DIST_OFF + (size_t)b * (TSTEPS * NCLS) + (size_t)t * NCLS;
        dout[dbase + c0] = d0 * mk;
        dout[dbase + c1] = d1 * mk;
        if (v2) dout[dbase + c2] = d2 * mk;

        /* max over classes >= 1 */
        float dm = (lane >= 1) ? d0 : -INFINITY;
        dm = fmaxf(dm, d1);
        if (v2) dm = fmaxf(dm, d2);
        #pragma unroll
        for (int off = 32; off; off >>= 1) dm = fmaxf(dm, __shfl_xor(dm, off));

        /* first class >= 1 achieving the max -> commitment */
        int cand = 0x7fffffff;
        if (lane >= 1 && d0 == dm) cand = c0;
        if (d1 == dm) cand = min(cand, c1);
        if (v2 && d2 == dm) cand = min(cand, c2);
        #pragma unroll
        for (int off = 32; off; off >>= 1) cand = min(cand, __shfl_xor(cand, off));
        if (lane == 0)
            dout[COMMIT_OFF + (size_t)t * BATCH_ + b] = (float)(cand - 1);

        /* onehot match list: ALL classes (incl. 0) where dist == max */
        if (d0 == dm)       { int p = atomicAdd(&cntS[r], 1); if (p < 8) listS[r][p] = c0; }
        if (d1 == dm)       { int p = atomicAdd(&cntS[r], 1); if (p < 8) listS[r][p] = c1; }
        if (v2 && d2 == dm) { int p = atomicAdd(&cntS[r], 1); if (p < 8) listS[r][p] = c2; }
    }
    __syncthreads();

    /* persist match list for next step's pi gather */
    if (tid < RPB) {
        int b = r0 + tid;
        int c = min(cntS[tid], 8);
        prevCnt[b] = c;
        for (int i = 0; i < c; ++i) prevList[b * 8 + i] = listS[tid][i];
    }
}

/* ------------------------------------------------------------------ */
extern "C" void kernel_launch(void* const* d_in, const int* in_sizes, int n_in,
                              void* d_out, int out_size, void* d_ws, size_t ws_size,
                              hipStream_t stream)
{
    (void)in_sizes; (void)n_in; (void)out_size; (void)ws_size;
    const float* inputs   = (const float*)d_in[0];
    const int*   obj_num  = (const int*)  d_in[1];
    const float* W_in     = (const float*)d_in[2];
    const float* b_in     = (const float*)d_in[3];
    const float* W_state  = (const float*)d_in[4];
    const float* b_state  = (const float*)d_in[5];
    const float* W_out    = (const float*)d_in[6];
    const float* b_out    = (const float*)d_in[7];
    const float* W_onehot = (const float*)d_in[8];
    const float* b_onehot = (const float*)d_in[9];
    const float* W_embed  = (const float*)d_in[10];
    const float* b_embed  = (const float*)d_in[11];

    float* out = (float*)d_out;
    float* ws  = (float*)d_ws;
    float* stateA = ws + WS_STATE;
    float* memB   = ws + WS_MEM;
    float* P_a    = ws + WS_PA;
    float* P_b    = ws + WS_PB;
    float* P0     = ws + WS_P0;
    float* E0     = ws + WS_E0;
    float* T0T    = ws + WS_T0T;
    float* T1b    = ws + WS_T1B;
    float* WoutT  = ws + WS_WOUTT;
    int*   prevCnt  = (int*)(ws + WS_LIST);
    int*   prevList = prevCnt + BATCH_;

    hipLaunchKernelGGL(prep_kernel, dim3(256), dim3(256), 0, stream,
                       W_out, WoutT, memB, P_a, P_b);
    hipLaunchKernelGGL(tab_kernel, dim3(240), dim3(256), 0, stream,
                       W_in, W_onehot, T0T);
    hipLaunchKernelGGL(t1b_kernel, dim3(NP / 256), dim3(256), 0, stream,
                       W_in, b_onehot, b_in, T1b);
    hipLaunchKernelGGL(k0_gemm_embed, dim3(64), dim3(256), 0, stream,
                       inputs, W_embed, b_embed, E0);
    hipLaunchKernelGGL(k1full_gemm, dim3(8 * 48), dim3(256), 0, stream,
                       E0, W_in, P0);

    for (int t = 0; t < TSTEPS; ++t) {
        if (t)
            hipLaunchKernelGGL(k1_gemm, dim3(640), dim3(256), 0, stream,
                               stateA, W_state, P_a, P_b);
        hipLaunchKernelGGL(k23_step, dim3(BATCH_ / RPB), dim3(256), 0, stream,
                           P_a, P_b, P0, T0T, T1b, memB, stateA, WoutT,
                           b_in, b_state, b_out, obj_num, prevCnt, prevList,
                           out, t);
    }
}

// Round 8
// 5309.862 us; speedup vs baseline: 1.3026x; 1.3026x over previous
//
#include <hip/hip_runtime.h>
#include <cmath>

#define BATCH_  1024
#define DIN     2048
#define HID     512
#define NCLS    151
#define TSTEPS  65
#define NP      3072   /* 6*HID : pi width */
#define NS      2560   /* 5*HID : ps width */

/* d_out layout (floats): dists (B,T,C) | commitments (T,B) | states (B,T,H) */
#define DIST_OFF   0
#define COMMIT_OFF (BATCH_*TSTEPS*NCLS)
#define STATES_OFF (COMMIT_OFF + TSTEPS*BATCH_)

/* workspace layout (float offsets) — high-water mark kept EXACTLY at the
   round-2 proven-safe footprint (~42 MB). Embed split-K partials alias
   into the P0 region (P0 is produced only after they are consumed).    */
#define WS_STATE  0                          /* 1024 x 512  state (out) */
#define WS_MEM    (WS_STATE + BATCH_*HID)    /* 1024 x 512  memory      */
#define WS_PA     (WS_MEM   + BATCH_*HID)    /* 1024 x 2560 ps partial K0 */
#define WS_PB     (WS_PA    + BATCH_*NS)     /* 1024 x 2560 ps partial K1 */
#define WS_P0     (WS_PB    + BATCH_*NS)     /* 1024 x 3072 pi at t=0   */
#define WS_E0     (WS_P0    + BATCH_*NP)     /* 1024 x 512  embed0      */
#define WS_T0T    (WS_E0    + BATCH_*HID)    /* 151 x 3072  pi table    */
#define WS_T1B    (WS_T0T   + NCLS*NP)       /* 3072  W_in@b_onehot+b_in */
#define WS_WOUTT  (WS_T1B   + NP)            /* 512 x 151   W_out^T     */
#define WS_LIST   (WS_WOUTT + HID*NCLS)      /* int: 1024 cnt + 1024*8  */
#define WS_EPART  WS_P0                      /* ALIAS: 4 x 1024 x 512   */

/* ------------------------------------------------------------------ */
__global__ __launch_bounds__(256) void prep_kernel(
    const float* __restrict__ W_out, float* __restrict__ WoutT,
    float* __restrict__ memB, float* __restrict__ P_a, float* __restrict__ P_b)
{
    int idx = blockIdx.x * 256 + threadIdx.x;
    int stride = gridDim.x * 256;
    for (int i = idx; i < HID * NCLS; i += stride) {
        int k = i / NCLS, c = i % NCLS;
        WoutT[i] = W_out[c * HID + k];
    }
    for (int i = idx; i < BATCH_ * HID; i += stride) memB[i] = 0.f;
    for (int i = idx; i < BATCH_ * NS; i += stride) { P_a[i] = 0.f; P_b[i] = 0.f; }
}

/* T0T[c][n] = sum_h W_in[n,h] * W_onehot[h,c]   (one-time)           */
__global__ __launch_bounds__(256) void tab_kernel(
    const float* __restrict__ W_in, const float* __restrict__ W_onehot,
    float* __restrict__ T0T)
{
    int nt = blockIdx.x % 48, ct = blockIdx.x / 48;      /* 48 x 5 blocks */
    int n  = nt * 64 + (threadIdx.x & 63);
    int q  = threadIdx.x >> 6;
    int c0 = ct * 32 + q * 8;
    float acc[8] = {};
    for (int h = 0; h < HID; ++h) {
        float w = W_in[(size_t)n * HID + h];
        const float* orow = W_onehot + (size_t)h * NCLS;
        #pragma unroll
        for (int j = 0; j < 8; ++j) {
            int c = c0 + j;
            acc[j] += w * orow[(c < NCLS) ? c : (NCLS - 1)];
        }
    }
    #pragma unroll
    for (int j = 0; j < 8; ++j) {
        int c = c0 + j;
        if (c < NCLS) T0T[(size_t)c * NP + n] = acc[j];
    }
}

__global__ __launch_bounds__(256) void t1b_kernel(
    const float* __restrict__ W_in, const float* __restrict__ b_onehot,
    const float* __restrict__ b_in, float* __restrict__ T1b)
{
    int n = blockIdx.x * 256 + threadIdx.x;
    float acc = b_in[n];
    for (int h = 0; h < HID; ++h)
        acc += W_in[(size_t)n * HID + h] * b_onehot[h];
    T1b[n] = acc;
}

/* ------------------------------------------------------------------ */
#define BM 128
#define BN 64
#define BKK 16

__device__ __forceinline__ void gemm_seg(
    const float* __restrict__ A, int lda,
    const float* __restrict__ W, int ldw,
    int kLen, int m0, int n0,
    float* As, float* Bs, float acc[8][4])
{
    const int tid = threadIdx.x;
    const int ar = tid >> 2;
    const int ak = (tid & 3) << 2;
    const int tx = tid & 15;
    const int ty = tid >> 4;

    for (int k0 = 0; k0 < kLen; k0 += BKK) {
        float4 a0 = *(const float4*)(A + (size_t)(m0 + ar)      * lda + (k0 + ak));
        float4 a1 = *(const float4*)(A + (size_t)(m0 + ar + 64) * lda + (k0 + ak));
        float4 b0 = *(const float4*)(W + (size_t)(n0 + ar)      * ldw + (k0 + ak));
        __syncthreads();
        As[(ak + 0) * BM + ar]      = a0.x;
        As[(ak + 1) * BM + ar]      = a0.y;
        As[(ak + 2) * BM + ar]      = a0.z;
        As[(ak + 3) * BM + ar]      = a0.w;
        As[(ak + 0) * BM + ar + 64] = a1.x;
        As[(ak + 1) * BM + ar + 64] = a1.y;
        As[(ak + 2) * BM + ar + 64] = a1.z;
        As[(ak + 3) * BM + ar + 64] = a1.w;
        Bs[(ak + 0) * BN + ar] = b0.x;
        Bs[(ak + 1) * BN + ar] = b0.y;
        Bs[(ak + 2) * BN + ar] = b0.z;
        Bs[(ak + 3) * BN + ar] = b0.w;
        __syncthreads();
        #pragma unroll
        for (int kk = 0; kk < BKK; ++kk) {
            float av[8], bv[4];
            *(float4*)(&av[0]) = *(const float4*)(&As[kk * BM + ty * 8]);
            *(float4*)(&av[4]) = *(const float4*)(&As[kk * BM + ty * 8 + 4]);
            *(float4*)(&bv[0]) = *(const float4*)(&Bs[kk * BN + tx * 4]);
            #pragma unroll
            for (int i = 0; i < 8; ++i)
                #pragma unroll
                for (int j = 0; j < 4; ++j)
                    acc[i][j] = fmaf(av[i], bv[j], acc[i][j]);
        }
    }
}

/* per-step ps partials = state @ W_state^T, split-K(2), 640 blocks.
   XCD-aware: bid%8 selects the n-slice so each XCD's L2 keeps its own
   W_state slice resident across all 64 steps.                         */
__global__ __launch_bounds__(256) void k1_gemm(
    const float* __restrict__ stateA, const float* __restrict__ W_state,
    float* __restrict__ P_a, float* __restrict__ P_b)
{
    __shared__ float As[BKK * BM];
    __shared__ float Bs[BKK * BN];
    float acc[8][4] = {};
    const int bid  = blockIdx.x;
    const int xcd  = bid & 7;
    const int idx  = bid >> 3;            /* 0..79 */
    const int ks   = (idx >= 40) ? 1 : 0;
    const int idx2 = idx - ks * 40;       /* 0..39 */
    const int mt   = idx2 & 7;            /* 8 m-tiles of 128 */
    const int ng   = idx2 >> 3;           /* 0..4 */
    const int m0   = mt * BM;
    const int n0   = (xcd * 5 + ng) * BN; /* XCD-local n-slice, max 2496 */

    gemm_seg(stateA + ks * 256, HID, W_state + ks * 256, HID, 256, m0, n0, As, Bs, acc);

    float* P = ks ? P_b : P_a;
    const int tx = threadIdx.x & 15, ty = threadIdx.x >> 4;
    #pragma unroll
    for (int i = 0; i < 8; ++i) {
        int row = m0 + ty * 8 + i;
        float4 v = make_float4(acc[i][0], acc[i][1], acc[i][2], acc[i][3]);
        *(float4*)(P + (size_t)row * NS + n0 + tx * 4) = v;
    }
}

/* one-time: Epart[s] = inputs[:, s*512..] @ W_embed[:, s*512..]^T,
   split-K(4). Output tile grid is 8m x 8n = 64 blocks per kseg ->
   grid 256 TOTAL. (Round-3/4 crash: 128 blocks/kseg drove n0 past the
   512-row W_embed -> OOB reads. Grid must be mtiles*ntiles*ksegs.)    */
__global__ __launch_bounds__(256) void k0_gemm_embed(
    const float* __restrict__ inputs, const float* __restrict__ W_embed,
    float* __restrict__ Epart)
{
    __shared__ float As[BKK * BM];
    __shared__ float Bs[BKK * BN];
    float acc[8][4] = {};
    const int bid  = blockIdx.x;
    const int kseg = bid >> 6;            /* 0..3 */
    const int rem  = bid & 63;            /* 0..63 */
    const int m0   = (rem & 7) * BM;      /* 0..896  */
    const int n0   = (rem >> 3) * BN;     /* 0..448  */
    const int kofs = kseg * 512;

    gemm_seg(inputs + kofs, DIN, W_embed + kofs, DIN, 512, m0, n0, As, Bs, acc);

    float* E = Epart + (size_t)kseg * BATCH_ * HID;
    const int tx = threadIdx.x & 15, ty = threadIdx.x >> 4;
    #pragma unroll
    for (int i = 0; i < 8; ++i) {
        int row = m0 + ty * 8 + i;
        float4 v = make_float4(acc[i][0], acc[i][1], acc[i][2], acc[i][3]);
        *(float4*)(E + (size_t)row * HID + n0 + tx * 4) = v;
    }
}

/* E0 = sum of 4 partials + bias (float4), grid 512 */
__global__ __launch_bounds__(256) void e0_reduce(
    const float* __restrict__ Epart, const float* __restrict__ b_embed,
    float* __restrict__ E0)
{
    int i4 = blockIdx.x * 256 + threadIdx.x;          /* 131072 float4s */
    const float4* p = (const float4*)Epart;
    float4 s = p[i4];
    #pragma unroll
    for (int sgi = 1; sgi < 4; ++sgi) {
        float4 q = p[(size_t)sgi * (BATCH_ * HID / 4) + i4];
        s.x += q.x; s.y += q.y; s.z += q.z; s.w += q.w;
    }
    float4 bb = *(const float4*)(b_embed + (i4 & 127) * 4);
    s.x += bb.x; s.y += bb.y; s.z += bb.z; s.w += bb.w;
    ((float4*)E0)[i4] = s;
}

/* one-time: P0 = E0 @ W_in^T  (grid 8x48 = 384). Overwrites the Epart
   alias region — safe, partials already consumed by e0_reduce.        */
__global__ __launch_bounds__(256) void k1full_gemm(
    const float* __restrict__ E0, const float* __restrict__ W_in,
    float* __restrict__ P0)
{
    __shared__ float As[BKK * BM];
    __shared__ float Bs[BKK * BN];
    float acc[8][4] = {};
    const int m0 = (blockIdx.x & 7) * BM;
    const int n0 = (blockIdx.x >> 3) * BN;

    gemm_seg(E0, HID, W_in, HID, HID, m0, n0, As, Bs, acc);

    const int tx = threadIdx.x & 15, ty = threadIdx.x >> 4;
    #pragma unroll
    for (int i = 0; i < 8; ++i) {
        int row = m0 + ty * 8 + i;
        float4 v = make_float4(acc[i][0], acc[i][1], acc[i][2], acc[i][3]);
        *(float4*)(P0 + (size_t)row * NP + n0 + tx * 4) = v;
    }
}

/* ------------------------------------------------------------------ */
/* K23: pi gather + gates -> out -> logits (K-split over 4 waves) ->  */
/* softmax -> argmax/ballot list.  RPB=2 rows per block, grid 512.    */
#define RPB 2

__global__ __launch_bounds__(256) void k23_step(
    const float* __restrict__ P_a, const float* __restrict__ P_b,
    const float* __restrict__ P0,  const float* __restrict__ T0T,
    const float* __restrict__ T1b,
    float* __restrict__ memB, float* __restrict__ stateA,
    const float* __restrict__ WoutT,
    const float* __restrict__ b_in, const float* __restrict__ b_state,
    const float* __restrict__ b_out,
    const int* __restrict__ obj_num,
    int* __restrict__ prevCnt, int* __restrict__ prevList,
    float* __restrict__ dout, int t)
{
    __shared__ float outS[RPB][HID];
    __shared__ float pB[4][64][4];

    const int tid = threadIdx.x;
    const int r0 = blockIdx.x * RPB;

    /* Phase A: pi (table or P0) + ps -> gates -> out/state/mem */
    for (int idx = tid; idx < RPB * HID; idx += 256) {
        int r = idx >> 9, h = idx & (HID - 1);
        int b = r0 + r;
        float pi[6];
        if (t == 0) {
            #pragma unroll
            for (int j = 0; j < 6; ++j)
                pi[j] = P0[(size_t)b * NP + j * HID + h] + b_in[j * HID + h];
        } else {
            #pragma unroll
            for (int j = 0; j < 6; ++j) pi[j] = T1b[j * HID + h];
            int cnt = prevCnt[b];
            for (int i = 0; i < cnt; ++i) {
                const float* trow = T0T + (size_t)prevList[b * 8 + i] * NP;
                #pragma unroll
                for (int j = 0; j < 6; ++j) pi[j] += trow[j * HID + h];
            }
        }
        float x[5];
        #pragma unroll
        for (int j = 0; j < 5; ++j)
            x[j] = pi[j] + P_a[(size_t)b * NS + j * HID + h]
                         + P_b[(size_t)b * NS + j * HID + h]
                         + b_state[j * HID + h];
        float ig = 1.f / (1.f + expf(-x[0]));
        float fg = 1.f / (1.f + expf(-x[1]));
        float mi = tanhf(x[2]);
        float og = 1.f / (1.f + expf(-x[3]));
        float hg = 1.f / (1.f + expf(-x[4]));
        float mo = memB[(size_t)b * HID + h];
        float nm = ig * mi + fg * mo;
        memB[(size_t)b * HID + h] = nm;
        float o  = og * tanhf(nm);
        o = hg * o + (1.f - hg) * pi[5];
        outS[r][h] = o;
        stateA[(size_t)b * HID + h] = o;
        float mk = (t < obj_num[b]) ? 1.f : 0.f;
        dout[STATES_OFF + (size_t)b * (TSTEPS * HID) + (size_t)t * HID + h] = o * mk;
    }
    __syncthreads();

    /* Phase B1: logit partials. wave w: row = w>>1, k-half = w&1 */
    const int w = tid >> 6, lane = tid & 63;
    {
        const int r  = w >> 1;
        const int kh = w & 1;
        int c0 = lane, c1 = 64 + lane, c2 = 128 + lane;
        bool v2 = (c2 < NCLS);
        int c2c = v2 ? c2 : (NCLS - 1);

        float a0 = kh ? 0.f : b_out[c0];
        float a1 = kh ? 0.f : b_out[c1];
        float a2 = kh ? 0.f : b_out[c2c];
        const int kbase = kh * 256;
        #pragma unroll 4
        for (int k = kbase; k < kbase + 256; ++k) {
            float ov = outS[r][k];
            const float* wr = WoutT + (size_t)k * NCLS;
            a0 = fmaf(ov, wr[c0], a0);
            a1 = fmaf(ov, wr[c1], a1);
            a2 = fmaf(ov, wr[c2c], a2);
        }
        pB[w][lane][0] = a0;
        pB[w][lane][1] = a1;
        pB[w][lane][2] = a2;
    }
    __syncthreads();

    /* Phase B2: waves 0,1 finish row w */
    if (w < RPB) {
        const int r = w;
        const int b = r0 + r;
        int c0 = lane, c1 = 64 + lane, c2 = 128 + lane;
        bool v2 = (c2 < NCLS);

        float a0 = pB[2 * r][lane][0] + pB[2 * r + 1][lane][0];
        float a1 = pB[2 * r][lane][1] + pB[2 * r + 1][lane][1];
        float a2 = pB[2 * r][lane][2] + pB[2 * r + 1][lane][2];

        float mx = fmaxf(a0, a1);
        if (v2) mx = fmaxf(mx, a2);
        #pragma unroll
        for (int off = 32; off; off >>= 1) mx = fmaxf(mx, __shfl_xor(mx, off));
        float e0 = expf(a0 - mx), e1 = expf(a1 - mx);
        float e2 = v2 ? expf(a2 - mx) : 0.f;
        float sm = e0 + e1 + e2;
        #pragma unroll
        for (int off = 32; off; off >>= 1) sm += __shfl_xor(sm, off);
        float d0 = e0 / sm, d1 = e1 / sm, d2 = e2 / sm;

        float mk = (t < obj_num[b]) ? 1.f : 0.f;
        size_t dbase = DIST_OFF + (size_t)b * (TSTEPS * NCLS) + (size_t)t * NCLS;
        dout[dbase + c0] = d0 * mk;
        dout[dbase + c1] = d1 * mk;
        if (v2) dout[dbase + c2] = d2 * mk;

        /* max over classes >= 1 */
        float dm = (lane >= 1) ? d0 : -INFINITY;
        dm = fmaxf(dm, d1);
        if (v2) dm = fmaxf(dm, d2);
        #pragma unroll
        for (int off = 32; off; off >>= 1) dm = fmaxf(dm, __shfl_xor(dm, off));

        /* ballot masks: all classes where dist == dm (incl. class 0) */
        unsigned long long m0 = __ballot(d0 == dm);
        unsigned long long m1 = __ballot(d1 == dm);
        unsigned long long m2 = __ballot(v2 && (d2 == dm));

        if (lane == 0) {
            /* commitment: first class >= 1 achieving max */
            unsigned long long mA = m0 & ~1ull;
            int cand;
            if (mA)      cand = __builtin_ctzll(mA);
            else if (m1) cand = 64 + __builtin_ctzll(m1);
            else         cand = 128 + __builtin_ctzll(m2);
            dout[COMMIT_OFF + (size_t)t * BATCH_ + b] = (float)(cand - 1);

            /* match list in ascending class order (deterministic) */
            int cnt = 0;
            unsigned long long mm = m0;
            while (mm) { int c = __builtin_ctzll(mm); mm &= mm - 1;
                         if (cnt < 8) prevList[b * 8 + cnt] = c; ++cnt; }
            mm = m1;
            while (mm) { int c = 64 + __builtin_ctzll(mm); mm &= mm - 1;
                         if (cnt < 8) prevList[b * 8 + cnt] = c; ++cnt; }
            mm = m2;
            while (mm) { int c = 128 + __builtin_ctzll(mm); mm &= mm - 1;
                         if (cnt < 8) prevList[b * 8 + cnt] = c; ++cnt; }
            prevCnt[b] = (cnt < 8) ? cnt : 8;
        }
    }
}

/* ------------------------------------------------------------------ */
extern "C" void kernel_launch(void* const* d_in, const int* in_sizes, int n_in,
                              void* d_out, int out_size, void* d_ws, size_t ws_size,
                              hipStream_t stream)
{
    (void)in_sizes; (void)n_in; (void)out_size; (void)ws_size;
    const float* inputs   = (const float*)d_in[0];
    const int*   obj_num  = (const int*)  d_in[1];
    const float* W_in     = (const float*)d_in[2];
    const float* b_in     = (const float*)d_in[3];
    const float* W_state  = (const float*)d_in[4];
    const float* b_state  = (const float*)d_in[5];
    const float* W_out    = (const float*)d_in[6];
    const float* b_out    = (const float*)d_in[7];
    const float* W_onehot = (const float*)d_in[8];
    const float* b_onehot = (const float*)d_in[9];
    const float* W_embed  = (const float*)d_in[10];
    const float* b_embed  = (const float*)d_in[11];

    float* out = (float*)d_out;
    float* ws  = (float*)d_ws;
    float* stateA = ws + WS_STATE;
    float* memB   = ws + WS_MEM;
    float* P_a    = ws + WS_PA;
    float* P_b    = ws + WS_PB;
    float* P0     = ws + WS_P0;
    float* E0     = ws + WS_E0;
    float* T0T    = ws + WS_T0T;
    float* T1b    = ws + WS_T1B;
    float* WoutT  = ws + WS_WOUTT;
    int*   prevCnt  = (int*)(ws + WS_LIST);
    int*   prevList = prevCnt + BATCH_;
    float* Epart  = ws + WS_EPART;   /* alias of P0 region */

    hipLaunchKernelGGL(prep_kernel, dim3(512), dim3(256), 0, stream,
                       W_out, WoutT, memB, P_a, P_b);
    hipLaunchKernelGGL(tab_kernel, dim3(240), dim3(256), 0, stream,
                       W_in, W_onehot, T0T);
    hipLaunchKernelGGL(t1b_kernel, dim3(NP / 256), dim3(256), 0, stream,
                       W_in, b_onehot, b_in, T1b);
    hipLaunchKernelGGL(k0_gemm_embed, dim3(256), dim3(256), 0, stream,
                       inputs, W_embed, Epart);
    hipLaunchKernelGGL(e0_reduce, dim3(512), dim3(256), 0, stream,
                       Epart, b_embed, E0);
    hipLaunchKernelGGL(k1full_gemm, dim3(8 * 48), dim3(256), 0, stream,
                       E0, W_in, P0);

    for (int t = 0; t < TSTEPS; ++t) {
        if (t)
            hipLaunchKernelGGL(k1_gemm, dim3(640), dim3(256), 0, stream,
                               stateA, W_state, P_a, P_b);
        hipLaunchKernelGGL(k23_step, dim3(BATCH_ / RPB), dim3(256), 0, stream,
                           P_a, P_b, P0, T0T, T1b, memB, stateA, WoutT,
                           b_in, b_state, b_out, obj_num, prevCnt, prevList,
                           out, t);
    }
}